// Round 3
// baseline (272.187 us; speedup 1.0000x reference)
//
#include <hip/hip_runtime.h>
#include <hip/hip_bf16.h>

// LSTMP cell: B=16384, I=512, H=512, K_gates = 1024, 4H = 2048.
// d_in: x[B,I] h_prev[B,H] c_prev[B,H] W[2048,1024] b[2048] gamma[512] beta[512] Wp[512,512]
// d_out: [ out (B*H f32) | cell (B*H f32) ]
//   out slot doubles as A_bf16 [16384][1024] scratch until K3 overwrites it.
// ws: [ s/o bf16 (B*H shorts, 16MB) | W_bf16 (2048*1024, 4MB) | Wp_bf16 (512*512, 0.5MB) ]

typedef __attribute__((ext_vector_type(4))) float f32x4;
typedef __attribute__((ext_vector_type(8))) short bf16x8;
typedef __attribute__((ext_vector_type(4))) short bf16x4;

#define NB 16384
#define NH 512

__device__ __forceinline__ short f2bf(float f) {
    union { float f; unsigned u; } v; v.f = f;
    unsigned r = v.u + 0x7FFFu + ((v.u >> 16) & 1u);   // RNE
    return (short)(r >> 16);
}
__device__ __forceinline__ float bf2f(short s) {
    union { unsigned u; float f; } v; v.u = ((unsigned)(unsigned short)s) << 16;
    return v.f;
}
__device__ __forceinline__ float sigmoidf_(float x) { return 1.0f / (1.0f + __expf(-x)); }
__device__ __forceinline__ float tanhf_(float x) { return 1.0f - 2.0f / (__expf(2.0f * x) + 1.0f); }

__device__ __forceinline__ void gld16(const void* g, void* l) {
    __builtin_amdgcn_global_load_lds(
        (const __attribute__((address_space(1))) void*)g,
        (__attribute__((address_space(3))) void*)l, 16, 0, 0);
}

// ---------------------------------------------------------------------------
// K0: fused conversion -- A_bf16 = bf16([x|h]), W_bf16 = bf16(W), Wp_bf16 = bf16(Wp)
// one grid-stride kernel over all 16B chunks (saves a launch + serialization gap)
// ---------------------------------------------------------------------------
__global__ __launch_bounds__(256)
void k_convert(const float* __restrict__ x, const float* __restrict__ h,
               const float* __restrict__ W, const float* __restrict__ Wp,
               short* __restrict__ Abf, short* __restrict__ Wbf,
               short* __restrict__ Wpbf)
{
    const long long nA  = (long long)NB * 256;          // 4,194,304 chunks of 4 f32
    const long long nW  = (long long)2048 * 1024 / 4;   //   524,288
    const long long nWp = (long long)512 * 512 / 4;     //    65,536
    long long i = (long long)blockIdx.x * 256 + threadIdx.x;
    const long long stride = (long long)gridDim.x * 256;
    for (; i < nA + nW + nWp; i += stride) {
        const float* src; short* dst;
        if (i < nA) {
            const int r  = (int)(i >> 8);
            const int c4 = (int)(i & 255);
            src = (c4 < 128) ? (x + (size_t)r * 512 + c4 * 4)
                             : (h + (size_t)r * 512 + (c4 - 128) * 4);
            dst = Abf + i * 4;
        } else if (i < nA + nW) {
            const long long j = i - nA;
            src = W + j * 4; dst = Wbf + j * 4;
        } else {
            const long long j = i - nA - nW;
            src = Wp + j * 4; dst = Wpbf + j * 4;
        }
        f32x4 v = *(const f32x4*)src;
        bf16x4 o;
#pragma unroll
        for (int j = 0; j < 4; ++j) o[j] = f2bf(v[j]);
        *(bf16x4*)dst = o;
    }
}

// ---------------------------------------------------------------------------
// K1: gates GEMM (bf16, gload_lds, 2-phase double-buffered) + gates + cell_raw
// grid (128, 16). Block tile 128(M) x [4 gates x 32 h](N). BK=64. LDS 64KB.
// Virtual col v = wc*64 + n*16 + c -> gate = n, h = h0 + wc*16 + c
// => acc[m][n][q] holds gate n of (row, h): no epilogue LDS round-trip.
// T3-minimum: STAGE(t+1) issued BEFORE compute(t); one barrier per K-step.
// ---------------------------------------------------------------------------
__global__ __launch_bounds__(256, 2)
void k_gates_cell(const short* __restrict__ Abf, const short* __restrict__ Wbf,
                  const float* __restrict__ c_prev, const float* __restrict__ bvec,
                  float* __restrict__ cell_raw, short* __restrict__ o_ws)
{
    __shared__ __align__(16) short As[2][128 * 64];
    __shared__ __align__(16) short Bs[2][128 * 64];

    const int tid  = threadIdx.x;
    const int lane = tid & 63;
    const int wid  = tid >> 6;
    const int wr = wid >> 1, wc = wid & 1;
    const int row0 = blockIdx.x * 128;
    const int h0   = blockIdx.y * 32;

    const f32x4 zero = {0.f, 0.f, 0.f, 0.f};
    f32x4 acc[4][4];
#pragma unroll
    for (int m = 0; m < 4; ++m)
#pragma unroll
        for (int n = 0; n < 4; ++n) acc[m][n] = zero;

    // staging: chunk ci = (wid*4+j)*64+lane covers LDS row=ci>>3, phys k8=lane&7.
    // read-side swizzle is byt^=(row&7)<<4, so source chunk = (lane&7)^(row&7).
    const int k8 = ((lane & 7) ^ (lane >> 3)) * 8;
    const int ldsc = (wid * 4) * 512;      // this wave's LDS chunk base (j=0)
    int aOff[4], bOff[4];
#pragma unroll
    for (int j = 0; j < 4; ++j) {
        const int row = (wid * 4 + j) * 8 + (lane >> 3);      // 0..127
        aOff[j] = (row0 + row) * 1024 + k8;
        const int gate = (row >> 4) & 3;
        const int wrow = gate * 512 + h0 + (row >> 6) * 16 + (row & 15);
        bOff[j] = wrow * 1024 + k8;
    }

    // prologue: stage tile 0 into buffer 0
#pragma unroll
    for (int j = 0; j < 4; ++j) {
        gld16(Abf + aOff[j], &As[0][ldsc + j * 512]);
        gld16(Wbf + bOff[j], &Bs[0][ldsc + j * 512]);
    }
    __syncthreads();                       // vmcnt(0) drain: tile 0 staged

    int cur = 0;
    for (int kt = 0; kt < 16; ++kt) {
        if (kt < 15) {                     // issue next-tile loads (fly under MFMA)
            const int kb = (kt + 1) * 64;
#pragma unroll
            for (int j = 0; j < 4; ++j) {
                gld16(Abf + aOff[j] + kb, &As[cur ^ 1][ldsc + j * 512]);
                gld16(Wbf + bOff[j] + kb, &Bs[cur ^ 1][ldsc + j * 512]);
            }
        }
        const short* Ac = As[cur];
        const short* Bc = Bs[cur];
#pragma unroll
        for (int kk = 0; kk < 64; kk += 32) {
            bf16x8 af[4], bfr[4];
#pragma unroll
            for (int m = 0; m < 4; ++m) {
                const int row = wr * 64 + m * 16 + (lane & 15);
                int byt = row * 128 + (kk + (lane >> 4) * 8) * 2;
                byt ^= (row & 7) << 4;
                af[m] = *(const bf16x8*)((const char*)Ac + byt);
            }
#pragma unroll
            for (int n = 0; n < 4; ++n) {
                const int row = wc * 64 + n * 16 + (lane & 15);
                int byt = row * 128 + (kk + (lane >> 4) * 8) * 2;
                byt ^= (row & 7) << 4;
                bfr[n] = *(const bf16x8*)((const char*)Bc + byt);
            }
#pragma unroll
            for (int m = 0; m < 4; ++m)
#pragma unroll
                for (int n = 0; n < 4; ++n)
                    acc[m][n] = __builtin_amdgcn_mfma_f32_16x16x32_bf16(af[m], bfr[n], acc[m][n], 0, 0, 0);
        }
        __syncthreads();   // drains vmcnt(0) (next tile staged) + all reads of cur done
        cur ^= 1;
    }

    // epilogue: thread owns all 4 gates of (row, hcol) for 16 rows
    const int hcol = h0 + wc * 16 + (lane & 15);
    float bias[4];
#pragma unroll
    for (int n = 0; n < 4; ++n) bias[n] = bvec[n * 512 + hcol];
#pragma unroll
    for (int m = 0; m < 4; ++m) {
        const int rbase = row0 + wr * 64 + m * 16 + ((lane >> 4) * 4);
#pragma unroll
        for (int q = 0; q < 4; ++q) {
            const size_t idx = (size_t)(rbase + q) * 512 + hcol;
            const float iv = acc[m][0][q] + bias[0];
            const float fv = acc[m][1][q] + bias[1];
            const float gv = acc[m][2][q] + bias[2];
            const float ov = acc[m][3][q] + bias[3];
            const float c = c_prev[idx];
            cell_raw[idx] = sigmoidf_(fv) * c + sigmoidf_(iv) * tanhf_(gv);
            o_ws[idx] = f2bf(sigmoidf_(ov));
        }
    }
}

// ---------------------------------------------------------------------------
// K2: per-row LayerNorm (in place) + s = sigma(o)*tanh(cell)  (in place in s_io)
// grid: 4096 x 256 (4 waves/block, 1 row each)
// ---------------------------------------------------------------------------
__global__ __launch_bounds__(256)
void k_layernorm(const float* __restrict__ gamma, const float* __restrict__ beta,
                 float* __restrict__ cell, short* __restrict__ s_io)
{
    const int r = blockIdx.x * 4 + (threadIdx.x >> 6);
    const int lane = threadIdx.x & 63;
    float* row = cell + (size_t)r * 512;
    f32x4 v0 = *(const f32x4*)(row + lane * 8);
    f32x4 v1 = *(const f32x4*)(row + lane * 8 + 4);
    float s1 = 0.f, s2 = 0.f;
#pragma unroll
    for (int j = 0; j < 4; ++j) {
        s1 += v0[j] + v1[j];
        s2 += v0[j] * v0[j] + v1[j] * v1[j];
    }
#pragma unroll
    for (int off = 32; off > 0; off >>= 1) {
        s1 += __shfl_xor(s1, off);
        s2 += __shfl_xor(s2, off);
    }
    const float mu  = s1 * (1.f / 512.f);
    const float var = s2 * (1.f / 512.f) - mu * mu;
    const float rs  = rsqrtf(var + 1e-5f);
    const f32x4 g0 = *(const f32x4*)(gamma + lane * 8);
    const f32x4 g1 = *(const f32x4*)(gamma + lane * 8 + 4);
    const f32x4 b0 = *(const f32x4*)(beta + lane * 8);
    const f32x4 b1 = *(const f32x4*)(beta + lane * 8 + 4);
    const bf16x8 o8 = *(const bf16x8*)(s_io + (size_t)r * 512 + lane * 8);
    f32x4 c0, c1; bf16x8 s8;
#pragma unroll
    for (int j = 0; j < 4; ++j) {
        c0[j] = (v0[j] - mu) * rs * g0[j] + b0[j];
        c1[j] = (v1[j] - mu) * rs * g1[j] + b1[j];
    }
#pragma unroll
    for (int j = 0; j < 4; ++j) {
        s8[j]     = f2bf(bf2f(o8[j])     * tanhf_(c0[j]));
        s8[j + 4] = f2bf(bf2f(o8[j + 4]) * tanhf_(c1[j]));
    }
    *(f32x4*)(row + lane * 8)     = c0;
    *(f32x4*)(row + lane * 8 + 4) = c1;
    *(bf16x8*)(s_io + (size_t)r * 512 + lane * 8) = s8;
}

// ---------------------------------------------------------------------------
// K3: out = s @ Wp^T  (M=16384, N=512, K=512), bf16, 2-phase double-buffered
// grid (128, 4)
// ---------------------------------------------------------------------------
__global__ __launch_bounds__(256, 2)
void k_proj(const short* __restrict__ s_ws, const short* __restrict__ Wpbf,
            float* __restrict__ out)
{
    __shared__ __align__(16) short As[2][128 * 64];
    __shared__ __align__(16) short Bs[2][128 * 64];
    const int tid = threadIdx.x;
    const int lane = tid & 63;
    const int wid = tid >> 6;
    const int wr = wid >> 1, wc = wid & 1;
    const int row0 = blockIdx.x * 128;
    const int col0 = blockIdx.y * 128;

    const f32x4 zero = {0.f, 0.f, 0.f, 0.f};
    f32x4 acc[4][4];
#pragma unroll
    for (int m = 0; m < 4; ++m)
#pragma unroll
        for (int n = 0; n < 4; ++n) acc[m][n] = zero;

    const int k8 = ((lane & 7) ^ (lane >> 3)) * 8;
    const int ldsc = (wid * 4) * 512;
    int aOff[4], bOff[4];
#pragma unroll
    for (int j = 0; j < 4; ++j) {
        const int row = (wid * 4 + j) * 8 + (lane >> 3);
        aOff[j] = (row0 + row) * 512 + k8;
        bOff[j] = (col0 + row) * 512 + k8;
    }

#pragma unroll
    for (int j = 0; j < 4; ++j) {
        gld16(s_ws + aOff[j], &As[0][ldsc + j * 512]);
        gld16(Wpbf + bOff[j], &Bs[0][ldsc + j * 512]);
    }
    __syncthreads();

    int cur = 0;
    for (int kt = 0; kt < 8; ++kt) {
        if (kt < 7) {
            const int kb = (kt + 1) * 64;
#pragma unroll
            for (int j = 0; j < 4; ++j) {
                gld16(s_ws + aOff[j] + kb, &As[cur ^ 1][ldsc + j * 512]);
                gld16(Wpbf + bOff[j] + kb, &Bs[cur ^ 1][ldsc + j * 512]);
            }
        }
        const short* Ac = As[cur];
        const short* Bc = Bs[cur];
#pragma unroll
        for (int kk = 0; kk < 64; kk += 32) {
            bf16x8 af[4], bfr[4];
#pragma unroll
            for (int m = 0; m < 4; ++m) {
                const int row = wr * 64 + m * 16 + (lane & 15);
                int byt = row * 128 + (kk + (lane >> 4) * 8) * 2;
                byt ^= (row & 7) << 4;
                af[m] = *(const bf16x8*)((const char*)Ac + byt);
            }
#pragma unroll
            for (int n = 0; n < 4; ++n) {
                const int row = wc * 64 + n * 16 + (lane & 15);
                int byt = row * 128 + (kk + (lane >> 4) * 8) * 2;
                byt ^= (row & 7) << 4;
                bfr[n] = *(const bf16x8*)((const char*)Bc + byt);
            }
#pragma unroll
            for (int m = 0; m < 4; ++m)
#pragma unroll
                for (int n = 0; n < 4; ++n)
                    acc[m][n] = __builtin_amdgcn_mfma_f32_16x16x32_bf16(af[m], bfr[n], acc[m][n], 0, 0, 0);
        }
        __syncthreads();
        cur ^= 1;
    }

#pragma unroll
    for (int m = 0; m < 4; ++m) {
        const int grow = row0 + wr * 64 + m * 16 + ((lane >> 4) * 4);
#pragma unroll
        for (int n = 0; n < 4; ++n) {
            const int gcol = col0 + wc * 64 + n * 16 + (lane & 15);
#pragma unroll
            for (int q = 0; q < 4; ++q)
                out[(size_t)(grow + q) * 512 + gcol] = acc[m][n][q];
        }
    }
}

extern "C" void kernel_launch(void* const* d_in, const int* in_sizes, int n_in,
                              void* d_out, int out_size, void* d_ws, size_t ws_size,
                              hipStream_t stream) {
    (void)in_sizes; (void)n_in; (void)out_size; (void)ws_size;
    const float* x      = (const float*)d_in[0];
    const float* h_prev = (const float*)d_in[1];
    const float* c_prev = (const float*)d_in[2];
    const float* W      = (const float*)d_in[3];
    const float* bvec   = (const float*)d_in[4];
    const float* gamma  = (const float*)d_in[5];
    const float* beta   = (const float*)d_in[6];
    const float* Wp     = (const float*)d_in[7];

    float* out  = (float*)d_out;                       // [B*H] f32 (final)
    float* cell = out + (size_t)NB * NH;               // [B*H] f32
    short* Abf  = (short*)d_out;                       // [B][1024] bf16 (dies before K3)
    short* s_io = (short*)d_ws;                        // [B*H] bf16: o, then s in place
    short* Wbf  = s_io + (size_t)NB * NH;              // [2048*1024] bf16
    short* Wpbf = Wbf + (size_t)2048 * 1024;           // [512*512] bf16

    k_convert<<<2048, 256, 0, stream>>>(x, h_prev, W, Wp, Abf, Wbf, Wpbf);
    dim3 g1(NB / 128, 2048 / 128);
    k_gates_cell<<<g1, 256, 0, stream>>>(Abf, Wbf, c_prev, bvec, cell, s_io);
    k_layernorm<<<NB / 4, 256, 0, stream>>>(gamma, beta, cell, s_io);
    dim3 g3(NB / 128, NH / 128);
    k_proj<<<g3, 256, 0, stream>>>(s_io, Wpbf, out);
}

// Round 4
// 258.288 us; speedup vs baseline: 1.0538x; 1.0538x over previous
//
#include <hip/hip_runtime.h>
#include <hip/hip_bf16.h>

// LSTMP cell: B=16384, I=512, H=512, K_gates = 1024, 4H = 2048.
// d_in: x[B,I] h_prev[B,H] c_prev[B,H] W[2048,1024] b[2048] gamma[512] beta[512] Wp[512,512]
// d_out: [ out (B*H f32) | cell (B*H f32) ]
//   out slot doubles as A_bf16 [16384][1024] scratch until K3 overwrites it.
// ws: [ s/o bf16 (B*H shorts, 16MB) | W_bf16 (2048*1024, 4MB) | Wp_bf16 (512*512, 0.5MB) ]
//
// R3 lesson (measured): explicit LDS dbuf (64KB) dropped occupancy 3->2 blocks/CU
// and regressed 92->105us. Reverted to single-buffer 32KB; raised min-waves/EU
// to 4 (68 VGPR <= 128 cap, 4x32KB = 128KB <= 160KB) for 4 blocks/CU.

typedef __attribute__((ext_vector_type(4))) float f32x4;
typedef __attribute__((ext_vector_type(8))) short bf16x8;
typedef __attribute__((ext_vector_type(4))) short bf16x4;

#define NB 16384
#define NH 512

__device__ __forceinline__ short f2bf(float f) {
    union { float f; unsigned u; } v; v.f = f;
    unsigned r = v.u + 0x7FFFu + ((v.u >> 16) & 1u);   // RNE
    return (short)(r >> 16);
}
__device__ __forceinline__ float bf2f(short s) {
    union { unsigned u; float f; } v; v.u = ((unsigned)(unsigned short)s) << 16;
    return v.f;
}
__device__ __forceinline__ float sigmoidf_(float x) { return 1.0f / (1.0f + __expf(-x)); }
__device__ __forceinline__ float tanhf_(float x) { return 1.0f - 2.0f / (__expf(2.0f * x) + 1.0f); }

__device__ __forceinline__ void gld16(const void* g, void* l) {
    __builtin_amdgcn_global_load_lds(
        (const __attribute__((address_space(1))) void*)g,
        (__attribute__((address_space(3))) void*)l, 16, 0, 0);
}

// ---------------------------------------------------------------------------
// K0: fused conversion -- A_bf16 = bf16([x|h]), W_bf16 = bf16(W), Wp_bf16 = bf16(Wp)
// ---------------------------------------------------------------------------
__global__ __launch_bounds__(256, 8)
void k_convert(const float* __restrict__ x, const float* __restrict__ h,
               const float* __restrict__ W, const float* __restrict__ Wp,
               short* __restrict__ Abf, short* __restrict__ Wbf,
               short* __restrict__ Wpbf)
{
    const long long nA  = (long long)NB * 256;          // 4,194,304 chunks of 4 f32
    const long long nW  = (long long)2048 * 1024 / 4;   //   524,288
    const long long nWp = (long long)512 * 512 / 4;     //    65,536
    long long i = (long long)blockIdx.x * 256 + threadIdx.x;
    const long long stride = (long long)gridDim.x * 256;
    for (; i < nA + nW + nWp; i += stride) {
        const float* src; short* dst;
        if (i < nA) {
            const int r  = (int)(i >> 8);
            const int c4 = (int)(i & 255);
            src = (c4 < 128) ? (x + (size_t)r * 512 + c4 * 4)
                             : (h + (size_t)r * 512 + (c4 - 128) * 4);
            dst = Abf + i * 4;
        } else if (i < nA + nW) {
            const long long j = i - nA;
            src = W + j * 4; dst = Wbf + j * 4;
        } else {
            const long long j = i - nA - nW;
            src = Wp + j * 4; dst = Wpbf + j * 4;
        }
        f32x4 v = *(const f32x4*)src;
        bf16x4 o;
#pragma unroll
        for (int j = 0; j < 4; ++j) o[j] = f2bf(v[j]);
        *(bf16x4*)dst = o;
    }
}

// ---------------------------------------------------------------------------
// K1: gates GEMM (bf16, gload_lds staged, single-buffer) + gates + cell_raw
// grid (128, 16). Block tile 128(M) x [4 gates x 32 h](N). BK=64. LDS 32KB.
// Virtual col v = wc*64 + n*16 + c -> gate = n, h = h0 + wc*16 + c
// => acc[m][n][q] holds gate n of (row, h): no epilogue LDS round-trip.
// ---------------------------------------------------------------------------
__global__ __launch_bounds__(256, 4)
void k_gates_cell(const short* __restrict__ Abf, const short* __restrict__ Wbf,
                  const float* __restrict__ c_prev, const float* __restrict__ bvec,
                  float* __restrict__ cell_raw, short* __restrict__ o_ws)
{
    __shared__ __align__(16) short As[128 * 64];
    __shared__ __align__(16) short Bs[128 * 64];

    const int tid  = threadIdx.x;
    const int lane = tid & 63;
    const int wid  = tid >> 6;
    const int wr = wid >> 1, wc = wid & 1;
    const int row0 = blockIdx.x * 128;
    const int h0   = blockIdx.y * 32;

    const f32x4 zero = {0.f, 0.f, 0.f, 0.f};
    f32x4 acc[4][4];
#pragma unroll
    for (int m = 0; m < 4; ++m)
#pragma unroll
        for (int n = 0; n < 4; ++n) acc[m][n] = zero;

    // staging: chunk ci = (wid*4+j)*64+lane covers LDS row=ci>>3, phys k8=lane&7.
    // read-side swizzle is byt^=(row&7)<<4, so source chunk = (lane&7)^(row&7).
    const int k8 = ((lane & 7) ^ (lane >> 3)) * 8;
    int aOff[4], bOff[4];
#pragma unroll
    for (int j = 0; j < 4; ++j) {
        const int row = (wid * 4 + j) * 8 + (lane >> 3);      // 0..127
        aOff[j] = (row0 + row) * 1024 + k8;
        const int gate = (row >> 4) & 3;
        const int wrow = gate * 512 + h0 + (row >> 6) * 16 + (row & 15);
        bOff[j] = wrow * 1024 + k8;
    }

    for (int kt = 0; kt < 16; ++kt) {
        const int kbase = kt * 64;
#pragma unroll
        for (int j = 0; j < 4; ++j) {
            gld16(Abf + aOff[j] + kbase, As + (wid * 4 + j) * 512);
            gld16(Wbf + bOff[j] + kbase, Bs + (wid * 4 + j) * 512);
        }
        __syncthreads();   // drains vmcnt(0): tile staged
#pragma unroll
        for (int kk = 0; kk < 64; kk += 32) {
            bf16x8 af[4], bfr[4];
#pragma unroll
            for (int m = 0; m < 4; ++m) {
                const int row = wr * 64 + m * 16 + (lane & 15);
                int byt = row * 128 + (kk + (lane >> 4) * 8) * 2;
                byt ^= (row & 7) << 4;
                af[m] = *(const bf16x8*)((const char*)As + byt);
            }
#pragma unroll
            for (int n = 0; n < 4; ++n) {
                const int row = wc * 64 + n * 16 + (lane & 15);
                int byt = row * 128 + (kk + (lane >> 4) * 8) * 2;
                byt ^= (row & 7) << 4;
                bfr[n] = *(const bf16x8*)((const char*)Bs + byt);
            }
#pragma unroll
            for (int m = 0; m < 4; ++m)
#pragma unroll
                for (int n = 0; n < 4; ++n)
                    acc[m][n] = __builtin_amdgcn_mfma_f32_16x16x32_bf16(af[m], bfr[n], acc[m][n], 0, 0, 0);
        }
        __syncthreads();   // readers done before next stage
    }

    // epilogue: thread owns all 4 gates of (row, hcol) for 16 rows
    const int hcol = h0 + wc * 16 + (lane & 15);
    float bias[4];
#pragma unroll
    for (int n = 0; n < 4; ++n) bias[n] = bvec[n * 512 + hcol];
#pragma unroll
    for (int m = 0; m < 4; ++m) {
        const int rbase = row0 + wr * 64 + m * 16 + ((lane >> 4) * 4);
#pragma unroll
        for (int q = 0; q < 4; ++q) {
            const size_t idx = (size_t)(rbase + q) * 512 + hcol;
            const float iv = acc[m][0][q] + bias[0];
            const float fv = acc[m][1][q] + bias[1];
            const float gv = acc[m][2][q] + bias[2];
            const float ov = acc[m][3][q] + bias[3];
            const float c = c_prev[idx];
            cell_raw[idx] = sigmoidf_(fv) * c + sigmoidf_(iv) * tanhf_(gv);
            o_ws[idx] = f2bf(sigmoidf_(ov));
        }
    }
}

// ---------------------------------------------------------------------------
// K2: per-row LayerNorm (in place) + s = sigma(o)*tanh(cell)  (in place in s_io)
// grid: 4096 x 256 (4 waves/block, 1 row each)
// ---------------------------------------------------------------------------
__global__ __launch_bounds__(256)
void k_layernorm(const float* __restrict__ gamma, const float* __restrict__ beta,
                 float* __restrict__ cell, short* __restrict__ s_io)
{
    const int r = blockIdx.x * 4 + (threadIdx.x >> 6);
    const int lane = threadIdx.x & 63;
    float* row = cell + (size_t)r * 512;
    f32x4 v0 = *(const f32x4*)(row + lane * 8);
    f32x4 v1 = *(const f32x4*)(row + lane * 8 + 4);
    float s1 = 0.f, s2 = 0.f;
#pragma unroll
    for (int j = 0; j < 4; ++j) {
        s1 += v0[j] + v1[j];
        s2 += v0[j] * v0[j] + v1[j] * v1[j];
    }
#pragma unroll
    for (int off = 32; off > 0; off >>= 1) {
        s1 += __shfl_xor(s1, off);
        s2 += __shfl_xor(s2, off);
    }
    const float mu  = s1 * (1.f / 512.f);
    const float var = s2 * (1.f / 512.f) - mu * mu;
    const float rs  = rsqrtf(var + 1e-5f);
    const f32x4 g0 = *(const f32x4*)(gamma + lane * 8);
    const f32x4 g1 = *(const f32x4*)(gamma + lane * 8 + 4);
    const f32x4 b0 = *(const f32x4*)(beta + lane * 8);
    const f32x4 b1 = *(const f32x4*)(beta + lane * 8 + 4);
    const bf16x8 o8 = *(const bf16x8*)(s_io + (size_t)r * 512 + lane * 8);
    f32x4 c0, c1; bf16x8 s8;
#pragma unroll
    for (int j = 0; j < 4; ++j) {
        c0[j] = (v0[j] - mu) * rs * g0[j] + b0[j];
        c1[j] = (v1[j] - mu) * rs * g1[j] + b1[j];
    }
#pragma unroll
    for (int j = 0; j < 4; ++j) {
        s8[j]     = f2bf(bf2f(o8[j])     * tanhf_(c0[j]));
        s8[j + 4] = f2bf(bf2f(o8[j + 4]) * tanhf_(c1[j]));
    }
    *(f32x4*)(row + lane * 8)     = c0;
    *(f32x4*)(row + lane * 8 + 4) = c1;
    *(bf16x8*)(s_io + (size_t)r * 512 + lane * 8) = s8;
}

// ---------------------------------------------------------------------------
// K3: out = s @ Wp^T  (M=16384, N=512, K=512), bf16, gload_lds, single-buffer
// grid (128, 4)
// ---------------------------------------------------------------------------
__global__ __launch_bounds__(256, 4)
void k_proj(const short* __restrict__ s_ws, const short* __restrict__ Wpbf,
            float* __restrict__ out)
{
    __shared__ __align__(16) short As[128 * 64];
    __shared__ __align__(16) short Bs[128 * 64];
    const int tid = threadIdx.x;
    const int lane = tid & 63;
    const int wid = tid >> 6;
    const int wr = wid >> 1, wc = wid & 1;
    const int row0 = blockIdx.x * 128;
    const int col0 = blockIdx.y * 128;

    const f32x4 zero = {0.f, 0.f, 0.f, 0.f};
    f32x4 acc[4][4];
#pragma unroll
    for (int m = 0; m < 4; ++m)
#pragma unroll
        for (int n = 0; n < 4; ++n) acc[m][n] = zero;

    const int k8 = ((lane & 7) ^ (lane >> 3)) * 8;
    int aOff[4], bOff[4];
#pragma unroll
    for (int j = 0; j < 4; ++j) {
        const int row = (wid * 4 + j) * 8 + (lane >> 3);
        aOff[j] = (row0 + row) * 512 + k8;
        bOff[j] = (col0 + row) * 512 + k8;
    }

    for (int kt = 0; kt < 8; ++kt) {
        const int kbase = kt * 64;
#pragma unroll
        for (int j = 0; j < 4; ++j) {
            gld16(s_ws + aOff[j] + kbase, As + (wid * 4 + j) * 512);
            gld16(Wpbf + bOff[j] + kbase, Bs + (wid * 4 + j) * 512);
        }
        __syncthreads();
#pragma unroll
        for (int kk = 0; kk < 64; kk += 32) {
            bf16x8 af[4], bfr[4];
#pragma unroll
            for (int m = 0; m < 4; ++m) {
                const int row = wr * 64 + m * 16 + (lane & 15);
                int byt = row * 128 + (kk + (lane >> 4) * 8) * 2;
                byt ^= (row & 7) << 4;
                af[m] = *(const bf16x8*)((const char*)As + byt);
            }
#pragma unroll
            for (int n = 0; n < 4; ++n) {
                const int row = wc * 64 + n * 16 + (lane & 15);
                int byt = row * 128 + (kk + (lane >> 4) * 8) * 2;
                byt ^= (row & 7) << 4;
                bfr[n] = *(const bf16x8*)((const char*)Bs + byt);
            }
#pragma unroll
            for (int m = 0; m < 4; ++m)
#pragma unroll
                for (int n = 0; n < 4; ++n)
                    acc[m][n] = __builtin_amdgcn_mfma_f32_16x16x32_bf16(af[m], bfr[n], acc[m][n], 0, 0, 0);
        }
        __syncthreads();
    }

#pragma unroll
    for (int m = 0; m < 4; ++m) {
        const int grow = row0 + wr * 64 + m * 16 + ((lane >> 4) * 4);
#pragma unroll
        for (int n = 0; n < 4; ++n) {
            const int gcol = col0 + wc * 64 + n * 16 + (lane & 15);
#pragma unroll
            for (int q = 0; q < 4; ++q)
                out[(size_t)(grow + q) * 512 + gcol] = acc[m][n][q];
        }
    }
}

extern "C" void kernel_launch(void* const* d_in, const int* in_sizes, int n_in,
                              void* d_out, int out_size, void* d_ws, size_t ws_size,
                              hipStream_t stream) {
    (void)in_sizes; (void)n_in; (void)out_size; (void)ws_size;
    const float* x      = (const float*)d_in[0];
    const float* h_prev = (const float*)d_in[1];
    const float* c_prev = (const float*)d_in[2];
    const float* W      = (const float*)d_in[3];
    const float* bvec   = (const float*)d_in[4];
    const float* gamma  = (const float*)d_in[5];
    const float* beta   = (const float*)d_in[6];
    const float* Wp     = (const float*)d_in[7];

    float* out  = (float*)d_out;                       // [B*H] f32 (final)
    float* cell = out + (size_t)NB * NH;               // [B*H] f32
    short* Abf  = (short*)d_out;                       // [B][1024] bf16 (dies before K3)
    short* s_io = (short*)d_ws;                        // [B*H] bf16: o, then s in place
    short* Wbf  = s_io + (size_t)NB * NH;              // [2048*1024] bf16
    short* Wpbf = Wbf + (size_t)2048 * 1024;           // [512*512] bf16

    k_convert<<<2048, 256, 0, stream>>>(x, h_prev, W, Wp, Abf, Wbf, Wpbf);
    dim3 g1(NB / 128, 2048 / 128);
    k_gates_cell<<<g1, 256, 0, stream>>>(Abf, Wbf, c_prev, bvec, cell, s_io);
    k_layernorm<<<NB / 4, 256, 0, stream>>>(gamma, beta, cell, s_io);
    dim3 g3(NB / 128, NH / 128);
    k_proj<<<g3, 256, 0, stream>>>(s_io, Wpbf, out);
}